// Round 1
// baseline (935.348 us; speedup 1.0000x reference)
//
#include <hip/hip_runtime.h>

#define IMW 1024
#define IMH 1024
#define NB  8
#define WIN 51
#define HALF 25

__device__ __forceinline__ int refl(int i, int n) {
    if (i < 0) i = -i;
    if (i >= n) i = 2 * n - 2 - i;
    return i;
}

// fp64 gray using the fp32-stored weight values (matches RGB_W.astype(float64))
__device__ __forceinline__ double gray_at(const float* __restrict__ in, long long pix) {
    const float* p = in + pix * 3;
    return (double)p[0] * (double)0.2989f
         + (double)p[1] * (double)0.5870f
         + (double)p[2] * (double)0.1140f;
}

__global__ void k0_init(unsigned long long* stats) {
    stats[0] = ~0ULL;  // min (bit-ordered, all gray >= 0)
    stats[1] = 0ULL;   // max
}

// One block per image row: horizontal 51-window sums of gray and gray^2 (fp64),
// plus global min/max of gray via bit-ordered u64 atomics.
__global__ __launch_bounds__(256) void k1_rowpass(const float* __restrict__ in,
                                                  double* __restrict__ hsum,
                                                  double* __restrict__ hsum2,
                                                  unsigned long long* __restrict__ stats) {
    __shared__ double sg[IMW];
    __shared__ double sg2[IMW];
    const int row = blockIdx.x;                 // 0 .. NB*IMH-1
    const long long base = (long long)row * IMW;
    const int t = threadIdx.x;

    double lmin = 1e300, lmax = -1e300;
    // strided fill for coalesced global reads
    for (int k = 0; k < 4; k++) {
        int x = t + 256 * k;
        double g = gray_at(in, base + x);
        sg[x] = g;
        sg2[x] = g * g;
        lmin = fmin(lmin, g);
        lmax = fmax(lmax, g);
    }
    __syncthreads();

    // each thread: sliding 51-window over 4 consecutive pixels
    const int p0 = t * 4;
    double s = 0.0, s2 = 0.0;
    for (int j = -HALF; j <= HALF; j++) {
        int ix = refl(p0 + j, IMW);
        s  += sg[ix];
        s2 += sg2[ix];
    }
    hsum[base + p0]  = s;
    hsum2[base + p0] = s2;
    for (int k = 1; k < 4; k++) {
        int p = p0 + k;
        int ia = refl(p + HALF, IMW);
        int is = refl(p - HALF - 1, IMW);
        s  += sg[ia]  - sg[is];
        s2 += sg2[ia] - sg2[is];
        hsum[base + p]  = s;
        hsum2[base + p] = s2;
    }

    // wave-level min/max reduce (wave = 64 lanes), then one atomic per wave
    for (int off = 32; off; off >>= 1) {
        lmin = fmin(lmin, __shfl_down(lmin, off));
        lmax = fmax(lmax, __shfl_down(lmax, off));
    }
    if ((t & 63) == 0) {
        atomicMin(stats + 0, (unsigned long long)__double_as_longlong(lmin));
        atomicMax(stats + 1, (unsigned long long)__double_as_longlong(lmax));
    }
}

// Column pass: vertical running 51-window sum over hsum/hsum2, final Sauvola
// compare. Thread per column, 64-row strips.
__global__ __launch_bounds__(256) void k2_colpass(const float* __restrict__ in,
                                                  const double* __restrict__ hsum,
                                                  const double* __restrict__ hsum2,
                                                  const unsigned long long* __restrict__ stats,
                                                  float* __restrict__ out) {
    const int x  = blockIdx.x * 256 + threadIdx.x;
    const int y0 = blockIdx.y * 64;
    const int b  = blockIdx.z;
    const long long ib = (long long)b * IMH * IMW;

    const double gmin = __longlong_as_double((long long)stats[0]);
    const double gmax = __longlong_as_double((long long)stats[1]);
    const double r = 0.5 * (gmax - gmin);

    double vs = 0.0, vs2 = 0.0;
    for (int j = -HALF; j <= HALF; j++) {
        int ry = refl(y0 + j, IMH);
        long long idx = ib + (long long)ry * IMW + x;
        vs  += hsum[idx];
        vs2 += hsum2[idx];
    }

    for (int y = y0; y < y0 + 64; y++) {
        double m   = vs  / 2601.0;
        double m2  = vs2 / 2601.0;
        double var = fmax(m2 - m * m, 0.0);
        double sd  = sqrt(var);
        double thresh = m * (1.0 + 0.2 * (sd / r - 1.0));
        long long pix = ib + (long long)y * IMW + x;
        double g = gray_at(in, pix);
        out[pix] = (g > thresh) ? 1.0f : 0.0f;

        int ra = refl(y + HALF + 1, IMH);
        int rs = refl(y - HALF, IMH);
        long long ia = ib + (long long)ra * IMW + x;
        long long is = ib + (long long)rs * IMW + x;
        vs  += hsum[ia]  - hsum[is];
        vs2 += hsum2[ia] - hsum2[is];
    }
}

extern "C" void kernel_launch(void* const* d_in, const int* in_sizes, int n_in,
                              void* d_out, int out_size, void* d_ws, size_t ws_size,
                              hipStream_t stream) {
    const float* in = (const float*)d_in[0];
    float* out = (float*)d_out;

    unsigned long long* stats = (unsigned long long*)d_ws;
    double* hsum  = (double*)((char*)d_ws + 256);
    double* hsum2 = hsum + (size_t)NB * IMH * IMW;

    hipLaunchKernelGGL(k0_init, dim3(1), dim3(1), 0, stream, stats);
    hipLaunchKernelGGL(k1_rowpass, dim3(NB * IMH), dim3(256), 0, stream,
                       in, hsum, hsum2, stats);
    hipLaunchKernelGGL(k2_colpass, dim3(IMW / 256, IMH / 64, NB), dim3(256), 0, stream,
                       in, hsum, hsum2, stats, out);
}

// Round 2
// 392.725 us; speedup vs baseline: 2.3817x; 2.3817x over previous
//
#include <hip/hip_runtime.h>

#define IMW 1024
#define IMH 1024
#define NB  8
#define HALF 25
#define STRIP 32

#define W_R ((double)0.2989f)
#define W_G ((double)0.5870f)
#define W_B ((double)0.1140f)

__device__ __forceinline__ int refl(int i, int n) {
    if (i < 0) i = -i;
    if (i >= n) i = 2 * n - 2 - i;
    return i;
}

// fp64 gray using the fp32-stored weight values (matches RGB_W.astype(float64))
__device__ __forceinline__ double gray_at(const float* __restrict__ in, long long pix) {
    const float* p = in + pix * 3;
    return (double)p[0] * W_R + (double)p[1] * W_G + (double)p[2] * W_B;
}

__global__ void k0_init(unsigned long long* stats) {
    stats[0] = ~0ULL;  // min (bit-ordered, all gray >= 0)
    stats[1] = 0ULL;   // max
}

// 51-window sum at pixel p from inclusive row cumsum C[0..IMW-1], reflect pad.
// straight part + left-reflected + right-reflected, each a C-difference.
__device__ __forceinline__ double wsum(const double* __restrict__ C, int p) {
    int a = p + HALF; if (a > IMW - 1) a = IMW - 1;
    int b = p - HALF - 1;
    double s = C[a] - (b >= 0 ? C[b] : 0.0);
    if (p <= HALF - 1)      s += C[HALF - p] - C[0];          // i<0 mirrored
    if (p >= IMW - HALF)    s += C[IMW - 2] - C[2*IMW - 2 - HALF - 1 - p]; // i>=IMW mirrored
    return s;
}

// One block per image row. Cumsum of gray/gray^2 via register prefix + wave
// shuffle scan (conflict-free), then 2-read window sums. Also global min/max.
__global__ __launch_bounds__(256) void k1_rowpass(const float* __restrict__ in,
                                                  double* __restrict__ hsum,
                                                  double* __restrict__ hsum2,
                                                  unsigned long long* __restrict__ stats) {
    __shared__ double cs1[IMW];
    __shared__ double cs2[IMW];
    __shared__ double wt1[4], wt2[4], bmin[4], bmax[4];
    const int row = blockIdx.x;                 // 0 .. NB*IMH-1
    const long long base = (long long)row * IMW;
    const int t = threadIdx.x;
    const int lane = t & 63, w = t >> 6;

    // 4 consecutive pixels per thread = 12 floats = 3x float4 (48B, 16B-aligned)
    const float4* p4 = (const float4*)(in + base * 3);
    float4 f0 = p4[3*t], f1 = p4[3*t+1], f2 = p4[3*t+2];
    double g0 = (double)f0.x*W_R + (double)f0.y*W_G + (double)f0.z*W_B;
    double g1 = (double)f0.w*W_R + (double)f1.x*W_G + (double)f1.y*W_B;
    double g2 = (double)f1.z*W_R + (double)f1.w*W_G + (double)f2.x*W_B;
    double g3 = (double)f2.y*W_R + (double)f2.z*W_G + (double)f2.w*W_B;

    double l1_0 = g0, l1_1 = l1_0 + g1, l1_2 = l1_1 + g2, l1_3 = l1_2 + g3;
    double q0 = g0*g0, q1 = g1*g1, q2 = g2*g2, q3 = g3*g3;
    double l2_0 = q0, l2_1 = l2_0 + q1, l2_2 = l2_1 + q2, l2_3 = l2_2 + q3;

    // block min/max -> one atomic pair per block
    double lmin = fmin(fmin(g0, g1), fmin(g2, g3));
    double lmax = fmax(fmax(g0, g1), fmax(g2, g3));
    for (int off = 32; off; off >>= 1) {
        lmin = fmin(lmin, __shfl_down(lmin, off));
        lmax = fmax(lmax, __shfl_down(lmax, off));
    }
    if (lane == 0) { bmin[w] = lmin; bmax[w] = lmax; }

    // wave-level inclusive scan of per-thread totals
    double v1 = l1_3, v2 = l2_3;
    for (int off = 1; off < 64; off <<= 1) {
        double u1 = __shfl_up(v1, off);
        double u2 = __shfl_up(v2, off);
        if (lane >= off) { v1 += u1; v2 += u2; }
    }
    if (lane == 63) { wt1[w] = v1; wt2[w] = v2; }
    __syncthreads();
    double e1 = v1 - l1_3, e2 = v2 - l2_3;   // exclusive prefix within wave
    for (int j = 0; j < w; j++) { e1 += wt1[j]; e2 += wt2[j]; }

    // write inclusive cumsum, 16B stores (bandwidth-limited, no conflicts)
    double2* c1 = (double2*)&cs1[4*t];
    double2* c2 = (double2*)&cs2[4*t];
    c1[0] = make_double2(e1 + l1_0, e1 + l1_1);
    c1[1] = make_double2(e1 + l1_2, e1 + l1_3);
    c2[0] = make_double2(e2 + l2_0, e2 + l2_1);
    c2[1] = make_double2(e2 + l2_2, e2 + l2_3);

    if (t == 0) {
        double m0 = fmin(fmin(bmin[0], bmin[1]), fmin(bmin[2], bmin[3]));
        double m1 = fmax(fmax(bmax[0], bmax[1]), fmax(bmax[2], bmax[3]));
        atomicMin(stats + 0, (unsigned long long)__double_as_longlong(m0));
        atomicMax(stats + 1, (unsigned long long)__double_as_longlong(m1));
    }
    __syncthreads();

    // outputs strided so lanes read/write consecutive addresses (conflict-free)
    for (int k = 0; k < 4; k++) {
        int p = t + 256 * k;
        hsum[base + p]  = wsum(cs1, p);
        hsum2[base + p] = wsum(cs2, p);
    }
}

// Column pass: vertical running 51-window sum over hsum/hsum2, final Sauvola
// compare. Thread per column, STRIP-row strips.
__global__ __launch_bounds__(256) void k2_colpass(const float* __restrict__ in,
                                                  const double* __restrict__ hsum,
                                                  const double* __restrict__ hsum2,
                                                  const unsigned long long* __restrict__ stats,
                                                  float* __restrict__ out) {
    const int x  = blockIdx.x * 256 + threadIdx.x;
    const int y0 = blockIdx.y * STRIP;
    const int b  = blockIdx.z;
    const long long ib = (long long)b * IMH * IMW;

    const double gmin = __longlong_as_double((long long)stats[0]);
    const double gmax = __longlong_as_double((long long)stats[1]);
    const double r = 0.5 * (gmax - gmin);

    double vs = 0.0, vs2 = 0.0;
    for (int j = -HALF; j <= HALF; j++) {
        int ry = refl(y0 + j, IMH);
        long long idx = ib + (long long)ry * IMW + x;
        vs  += hsum[idx];
        vs2 += hsum2[idx];
    }

    for (int y = y0; y < y0 + STRIP; y++) {
        double m   = vs  / 2601.0;
        double m2  = vs2 / 2601.0;
        double var = fmax(m2 - m * m, 0.0);
        double sd  = sqrt(var);
        double thresh = m * (1.0 + 0.2 * (sd / r - 1.0));
        long long pix = ib + (long long)y * IMW + x;
        double g = gray_at(in, pix);
        out[pix] = (g > thresh) ? 1.0f : 0.0f;

        int ra = refl(y + HALF + 1, IMH);
        int rs = refl(y - HALF, IMH);
        vs  += hsum[ib + (long long)ra * IMW + x]  - hsum[ib + (long long)rs * IMW + x];
        vs2 += hsum2[ib + (long long)ra * IMW + x] - hsum2[ib + (long long)rs * IMW + x];
    }
}

extern "C" void kernel_launch(void* const* d_in, const int* in_sizes, int n_in,
                              void* d_out, int out_size, void* d_ws, size_t ws_size,
                              hipStream_t stream) {
    const float* in = (const float*)d_in[0];
    float* out = (float*)d_out;

    unsigned long long* stats = (unsigned long long*)d_ws;
    double* hsum  = (double*)((char*)d_ws + 256);
    double* hsum2 = hsum + (size_t)NB * IMH * IMW;

    hipLaunchKernelGGL(k0_init, dim3(1), dim3(1), 0, stream, stats);
    hipLaunchKernelGGL(k1_rowpass, dim3(NB * IMH), dim3(256), 0, stream,
                       in, hsum, hsum2, stats);
    hipLaunchKernelGGL(k2_colpass, dim3(IMW / 256, IMH / STRIP, NB), dim3(256), 0, stream,
                       in, hsum, hsum2, stats, out);
}

// Round 3
// 258.577 us; speedup vs baseline: 3.6173x; 1.5188x over previous
//
#include <hip/hip_runtime.h>

#define IMW 1024
#define IMH 1024
#define NB  8
#define HALF 25
#define STRIP 32

#define W_R ((double)0.2989f)
#define W_G ((double)0.5870f)
#define W_B ((double)0.1140f)

__device__ __forceinline__ int refl(int i, int n) {
    if (i < 0) i = -i;
    if (i >= n) i = 2 * n - 2 - i;
    return i;
}

// 51-window sum at pixel p from inclusive row cumsum C[0..IMW-1], reflect pad.
__device__ __forceinline__ double wsum(const double* __restrict__ C, int p) {
    int a = p + HALF; if (a > IMW - 1) a = IMW - 1;
    int b = p - HALF - 1;
    double s = C[a] - (b >= 0 ? C[b] : 0.0);
    if (p <= HALF - 1)      s += C[HALF - p] - C[0];                        // i<0 mirrored
    if (p >= IMW - HALF)    s += C[IMW - 2] - C[2*IMW - 2 - HALF - 1 - p];  // i>=IMW mirrored
    return s;
}

// One block per image row. Cumsum of gray/gray^2 via register prefix + wave
// shuffle scan, 2-read window sums. Per-block min/max -> plain store (NO atomics).
__global__ __launch_bounds__(256) void k1_rowpass(const float* __restrict__ in,
                                                  double* __restrict__ hsum,
                                                  double* __restrict__ hsum2,
                                                  double2* __restrict__ blockstats) {
    __shared__ double cs1[IMW];
    __shared__ double cs2[IMW];
    __shared__ double wt1[4], wt2[4], bmin[4], bmax[4];
    const int row = blockIdx.x;                 // 0 .. NB*IMH-1
    const long long base = (long long)row * IMW;
    const int t = threadIdx.x;
    const int lane = t & 63, w = t >> 6;

    // 4 consecutive pixels per thread = 12 floats = 3x float4 (48B, 16B-aligned)
    const float4* p4 = (const float4*)(in + base * 3);
    float4 f0 = p4[3*t], f1 = p4[3*t+1], f2 = p4[3*t+2];
    double g0 = (double)f0.x*W_R + (double)f0.y*W_G + (double)f0.z*W_B;
    double g1 = (double)f0.w*W_R + (double)f1.x*W_G + (double)f1.y*W_B;
    double g2 = (double)f1.z*W_R + (double)f1.w*W_G + (double)f2.x*W_B;
    double g3 = (double)f2.y*W_R + (double)f2.z*W_G + (double)f2.w*W_B;

    double l1_0 = g0, l1_1 = l1_0 + g1, l1_2 = l1_1 + g2, l1_3 = l1_2 + g3;
    double q0 = g0*g0, q1 = g1*g1, q2 = g2*g2, q3 = g3*g3;
    double l2_0 = q0, l2_1 = l2_0 + q1, l2_2 = l2_1 + q2, l2_3 = l2_2 + q3;

    // block min/max
    double lmin = fmin(fmin(g0, g1), fmin(g2, g3));
    double lmax = fmax(fmax(g0, g1), fmax(g2, g3));
    for (int off = 32; off; off >>= 1) {
        lmin = fmin(lmin, __shfl_down(lmin, off));
        lmax = fmax(lmax, __shfl_down(lmax, off));
    }
    if (lane == 0) { bmin[w] = lmin; bmax[w] = lmax; }

    // wave-level inclusive scan of per-thread totals
    double v1 = l1_3, v2 = l2_3;
    for (int off = 1; off < 64; off <<= 1) {
        double u1 = __shfl_up(v1, off);
        double u2 = __shfl_up(v2, off);
        if (lane >= off) { v1 += u1; v2 += u2; }
    }
    if (lane == 63) { wt1[w] = v1; wt2[w] = v2; }
    __syncthreads();
    double e1 = v1 - l1_3, e2 = v2 - l2_3;   // exclusive prefix within wave
    for (int j = 0; j < w; j++) { e1 += wt1[j]; e2 += wt2[j]; }

    // write inclusive cumsum, 16B stores
    double2* c1 = (double2*)&cs1[4*t];
    double2* c2 = (double2*)&cs2[4*t];
    c1[0] = make_double2(e1 + l1_0, e1 + l1_1);
    c1[1] = make_double2(e1 + l1_2, e1 + l1_3);
    c2[0] = make_double2(e2 + l2_0, e2 + l2_1);
    c2[1] = make_double2(e2 + l2_2, e2 + l2_3);

    if (t == 0) {
        double m0 = fmin(fmin(bmin[0], bmin[1]), fmin(bmin[2], bmin[3]));
        double m1 = fmax(fmax(bmax[0], bmax[1]), fmax(bmax[2], bmax[3]));
        blockstats[row] = make_double2(m0, m1);   // plain store, no contention
    }
    __syncthreads();

    for (int k = 0; k < 4; k++) {
        int p = t + 256 * k;
        hsum[base + p]  = wsum(cs1, p);
        hsum2[base + p] = wsum(cs2, p);
    }
}

// Single-block tree reduce of 8192 per-row {min,max} pairs -> stats[0..1].
__global__ __launch_bounds__(1024) void k1b_reduce(const double2* __restrict__ blockstats,
                                                   double* __restrict__ stats) {
    __shared__ double smin[16], smax[16];
    const int t = threadIdx.x, lane = t & 63, w = t >> 6;
    double mn = 1e300, mx = -1e300;
    for (int i = t; i < NB * IMH; i += 1024) {
        double2 v = blockstats[i];
        mn = fmin(mn, v.x);
        mx = fmax(mx, v.y);
    }
    for (int off = 32; off; off >>= 1) {
        mn = fmin(mn, __shfl_down(mn, off));
        mx = fmax(mx, __shfl_down(mx, off));
    }
    if (lane == 0) { smin[w] = mn; smax[w] = mx; }
    __syncthreads();
    if (t == 0) {
        double a = smin[0], b = smax[0];
        for (int j = 1; j < 16; j++) { a = fmin(a, smin[j]); b = fmax(b, smax[j]); }
        stats[0] = a;
        stats[1] = b;
    }
}

// Column pass: 2 columns/thread (double2 loads), vertical running 51-window.
__global__ __launch_bounds__(256) void k2_colpass(const float* __restrict__ in,
                                                  const double* __restrict__ hsum,
                                                  const double* __restrict__ hsum2,
                                                  const double* __restrict__ stats,
                                                  float* __restrict__ out) {
    const int x0 = (blockIdx.x * 256 + threadIdx.x) * 2;
    const int y0 = blockIdx.y * STRIP;
    const int b  = blockIdx.z;
    const long long ib = (long long)b * IMH * IMW;

    const double r = 0.5 * (stats[1] - stats[0]);

    double2 vs = make_double2(0.0, 0.0), vs2 = make_double2(0.0, 0.0);
    for (int j = -HALF; j <= HALF; j++) {
        int ry = refl(y0 + j, IMH);
        long long idx = ib + (long long)ry * IMW + x0;
        double2 a = *(const double2*)(hsum + idx);
        double2 c = *(const double2*)(hsum2 + idx);
        vs.x += a.x; vs.y += a.y;
        vs2.x += c.x; vs2.y += c.y;
    }

    for (int y = y0; y < y0 + STRIP; y++) {
        long long pix = ib + (long long)y * IMW + x0;
        // 2 pixels = 6 floats, 8B-aligned: 3x float2
        const float2* p2 = (const float2*)(in + pix * 3);
        float2 a0 = p2[0], a1 = p2[1], a2 = p2[2];
        double ga = (double)a0.x*W_R + (double)a0.y*W_G + (double)a1.x*W_B;
        double gb = (double)a1.y*W_R + (double)a2.x*W_G + (double)a2.y*W_B;

        double m_a   = vs.x  / 2601.0, m_b   = vs.y  / 2601.0;
        double m2_a  = vs2.x / 2601.0, m2_b  = vs2.y / 2601.0;
        double sd_a  = sqrt(fmax(m2_a - m_a * m_a, 0.0));
        double sd_b  = sqrt(fmax(m2_b - m_b * m_b, 0.0));
        double th_a  = m_a * (1.0 + 0.2 * (sd_a / r - 1.0));
        double th_b  = m_b * (1.0 + 0.2 * (sd_b / r - 1.0));
        *(float2*)(out + pix) = make_float2(ga > th_a ? 1.0f : 0.0f,
                                            gb > th_b ? 1.0f : 0.0f);

        int ra = refl(y + HALF + 1, IMH);
        int rs = refl(y - HALF, IMH);
        long long iadd = ib + (long long)ra * IMW + x0;
        long long isub = ib + (long long)rs * IMW + x0;
        double2 aa = *(const double2*)(hsum + iadd);
        double2 as = *(const double2*)(hsum + isub);
        double2 ca = *(const double2*)(hsum2 + iadd);
        double2 cs = *(const double2*)(hsum2 + isub);
        vs.x  += aa.x - as.x;  vs.y  += aa.y - as.y;
        vs2.x += ca.x - cs.x;  vs2.y += ca.y - cs.y;
    }
}

extern "C" void kernel_launch(void* const* d_in, const int* in_sizes, int n_in,
                              void* d_out, int out_size, void* d_ws, size_t ws_size,
                              hipStream_t stream) {
    const float* in = (const float*)d_in[0];
    float* out = (float*)d_out;

    double* stats = (double*)d_ws;                              // 2 doubles
    double2* blockstats = (double2*)((char*)d_ws + 256);        // 8192 double2
    double* hsum  = (double*)((char*)d_ws + 256 + (size_t)NB * IMH * sizeof(double2));
    double* hsum2 = hsum + (size_t)NB * IMH * IMW;

    hipLaunchKernelGGL(k1_rowpass, dim3(NB * IMH), dim3(256), 0, stream,
                       in, hsum, hsum2, blockstats);
    hipLaunchKernelGGL(k1b_reduce, dim3(1), dim3(1024), 0, stream,
                       blockstats, stats);
    hipLaunchKernelGGL(k2_colpass, dim3(IMW / 512, IMH / STRIP, NB), dim3(256), 0, stream,
                       in, hsum, hsum2, stats, out);
}